// Round 1
// baseline (88.073 us; speedup 1.0000x reference)
//
#include <hip/hip_runtime.h>

// Sparse FM scorer: x (p=900000) has ~52 nonzeros (1 user one-hot, 1 item
// one-hot, 50-item basket). All terms are linear/bilinear in the nonzeros,
// so we scan x, compact (idx,val), gather ~52 embedding rows, and combine.
// Avoids touching u_V/b_V (358 MB) beyond ~26 KB of gathered rows.

#define NUSR 500000
#define NITM 200000
#define KDIM 128
#define MAXNZ 1024   // capacity for compacted nonzeros (actual ~52)

__global__ void k_init(int* cnt) {
    if (threadIdx.x == 0 && blockIdx.x == 0) *cnt = 0;
}

__global__ __launch_bounds__(256) void k_scan(
        const float* __restrict__ x, int p,
        int* __restrict__ cnt, int* __restrict__ idxs,
        float* __restrict__ vals, int cap) {
    int base = 4 * (blockIdx.x * blockDim.x + threadIdx.x);
    if (base >= p) return;
    float v[4];
    if (base + 3 < p) {
        const float4 f = *reinterpret_cast<const float4*>(x + base);
        v[0] = f.x; v[1] = f.y; v[2] = f.z; v[3] = f.w;
    } else {
        #pragma unroll
        for (int j = 0; j < 4; j++) v[j] = (base + j < p) ? x[base + j] : 0.0f;
    }
    #pragma unroll
    for (int j = 0; j < 4; j++) {
        if (v[j] != 0.0f) {
            int pos = atomicAdd(cnt, 1);
            if (pos < cap) { idxs[pos] = base + j; vals[pos] = v[j]; }
        }
    }
}

// One wave (64 lanes). Lane l owns embedding components l and l+64 (K=128).
__global__ __launch_bounds__(64) void k_final(
        const int* __restrict__ cnt,
        const int* __restrict__ idxs, const float* __restrict__ vals,
        const float* __restrict__ w0, const float* __restrict__ w_bias,
        const float* __restrict__ uV, const float* __restrict__ bV,
        float* __restrict__ out, int cap) {
    __shared__ int   s_idx[MAXNZ];
    __shared__ float s_val[MAXNZ];
    int m = *cnt;
    if (m > cap)   m = cap;
    if (m > MAXNZ) m = MAXNZ;
    const int lane = threadIdx.x;

    for (int e = lane; e < m; e += 64) { s_idx[e] = idxs[e]; s_val[e] = vals[e]; }
    __syncthreads();

    // Sort by index (atomic append order is nondeterministic) so the
    // floating-point accumulation order is identical every call.
    if (lane == 0) {
        for (int a = 1; a < m; a++) {
            int ia = s_idx[a]; float va = s_val[a]; int b = a - 1;
            while (b >= 0 && s_idx[b] > ia) {
                s_idx[b + 1] = s_idx[b]; s_val[b + 1] = s_val[b]; b--;
            }
            s_idx[b + 1] = ia; s_val[b + 1] = va;
        }
    }
    __syncthreads();

    float u0 = 0.f, u1 = 0.f;   // u_vec components (lane, lane+64)
    float t0 = 0.f, t1 = 0.f;   // t_vec
    float sv0 = 0.f, sv1 = 0.f; // s
    float sqp = 0.f;            // partial of sq (summed over owned k)
    float bias = 0.f;           // identical in every lane (uniform loads)

    for (int e = 0; e < m; e++) {
        const int i = s_idx[e];       // uniform across lanes -> no divergence
        const float v = s_val[e];
        bias += v * w_bias[i];
        if (i < NUSR) {
            const float* r = uV + (size_t)i * KDIM;
            u0 += v * r[lane]; u1 += v * r[lane + 64];
        } else if (i < NUSR + NITM) {
            const float* r = bV + (size_t)(i - NUSR) * KDIM;
            t0 += v * r[lane]; t1 += v * r[lane + 64];
        } else {
            const float* r = bV + (size_t)(i - NUSR - NITM) * KDIM;
            const float a = r[lane], b = r[lane + 64];
            sv0 += v * a; sv1 += v * b;
            sqp += v * (a * a + b * b);
        }
    }

    // Per-lane partial dot products, then 64-lane shuffle reduction.
    float ut = u0 * t0 + u1 * t1;     // dot(u_vec, t_vec)
    float tb = t0 * sv0 + t1 * sv1;   // dot(t_vec, s)
    float ss = sv0 * sv0 + sv1 * sv1; // dot(s, s)
    float ub = u0 * sv0 + u1 * sv1;   // dot(u_vec, s)
    float sq = sqp;
    #pragma unroll
    for (int off = 32; off > 0; off >>= 1) {
        ut += __shfl_down(ut, off);
        tb += __shfl_down(tb, off);
        ss += __shfl_down(ss, off);
        ub += __shfl_down(ub, off);
        sq += __shfl_down(sq, off);
    }
    if (lane == 0) {
        out[0] = w0[0] + bias + ut + tb + 0.5f * (ss - sq) + ub;
    }
}

extern "C" void kernel_launch(void* const* d_in, const int* in_sizes, int n_in,
                              void* d_out, int out_size, void* d_ws, size_t ws_size,
                              hipStream_t stream) {
    // inputs: 0:x 1:delta(unused) 2:pmi(unused) 3:w_0 4:w_bias 5:u_V 6:b_V
    const float* x      = (const float*)d_in[0];
    const float* w0     = (const float*)d_in[3];
    const float* w_bias = (const float*)d_in[4];
    const float* uV     = (const float*)d_in[5];
    const float* bV     = (const float*)d_in[6];
    float* out = (float*)d_out;
    const int p = in_sizes[0];

    char* ws = (char*)d_ws;
    int* cnt = (int*)ws;
    int cap = MAXNZ;
    const int avail = (int)((ws_size > 64 ? ws_size - 64 : 0) / 8);
    if (avail < cap) cap = avail;
    int*   idxs = (int*)(ws + 64);
    float* vals = (float*)(ws + 64 + (size_t)cap * 4);

    k_init<<<1, 64, 0, stream>>>(cnt);

    const int n4 = (p + 3) / 4;
    const int blocks = (n4 + 255) / 256;
    k_scan<<<blocks, 256, 0, stream>>>(x, p, cnt, idxs, vals, cap);

    k_final<<<1, 64, 0, stream>>>(cnt, idxs, vals, w0, w_bias, uV, bV, out, cap);
}

// Round 2
// 33.804 us; speedup vs baseline: 2.6054x; 2.6054x over previous
//
#include <hip/hip_runtime.h>

// Sparse FM scorer: x (p=900000) has ~52 nonzeros (1 user one-hot, 1 item
// one-hot, 50-item basket). All output terms are linear/bilinear in the
// nonzeros: scan x, compact (idx,val), gather ~52 embedding rows, combine.
//
// Single fused kernel (scan + last-block finalize) + a 128 B memset for the
// counters. Finalize uses a parallel rank-sort (determinism of summation
// order) and 4-wave-parallel row gather.

#define NUSR 500000
#define NITM 200000
#define KDIM 128
#define MAXNZ 256   // capacity for compacted nonzeros (actual ~52)

__global__ __launch_bounds__(256) void k_fused(
        const float* __restrict__ x, int p,
        int* __restrict__ cnt, int* __restrict__ done,
        int* __restrict__ idxs, float* __restrict__ vals, int cap,
        const float* __restrict__ w0, const float* __restrict__ w_bias,
        const float* __restrict__ uV, const float* __restrict__ bV,
        float* __restrict__ out, int nblocks) {
    // ---------------- scan phase (all blocks) ----------------
    const int tid  = blockIdx.x * blockDim.x + threadIdx.x;
    const int base = 4 * tid;
    if (base < p) {
        float v[4];
        if (base + 3 < p) {
            const float4 f = *reinterpret_cast<const float4*>(x + base);
            v[0] = f.x; v[1] = f.y; v[2] = f.z; v[3] = f.w;
        } else {
            #pragma unroll
            for (int j = 0; j < 4; j++) v[j] = (base + j < p) ? x[base + j] : 0.0f;
        }
        #pragma unroll
        for (int j = 0; j < 4; j++) {
            if (v[j] != 0.0f) {
                int pos = atomicAdd(cnt, 1);
                if (pos < cap) { idxs[pos] = base + j; vals[pos] = v[j]; }
            }
        }
    }

    // ---------------- last-block handoff ----------------
    __syncthreads();               // drains this block's global stores (vmcnt)
    __shared__ int is_last;
    if (threadIdx.x == 0) {
        __threadfence();           // device-scope release of our idxs/vals
        int prev = atomicAdd(done, 1);
        is_last = (prev == nblocks - 1) ? 1 : 0;
    }
    __syncthreads();
    if (!is_last) return;
    __threadfence();               // acquire: see every block's idxs/vals

    // ---------------- finalize (last block only, 256 thr = 4 waves) -------
    __shared__ int   a_idx[MAXNZ];
    __shared__ float a_val[MAXNZ];
    __shared__ int   b_idx[MAXNZ];
    __shared__ float b_val[MAXNZ];
    __shared__ float part[7][4][64];
    __shared__ float bias_part[4];

    int m = atomicAdd(cnt, 0);     // atomic load, device scope
    if (m > cap)   m = cap;
    if (m > MAXNZ) m = MAXNZ;

    for (int e = threadIdx.x; e < m; e += 256) {
        a_idx[e] = idxs[e];
        a_val[e] = vals[e];
    }
    __syncthreads();

    // Parallel rank-sort by index: rank = #{f : idx[f] < idx[e], ties by f}.
    // Atomic append order is nondeterministic; sorting fixes summation order.
    for (int e = threadIdx.x; e < m; e += 256) {
        const int ie = a_idx[e];
        int r = 0;
        for (int f = 0; f < m; f++) {
            const int jf = a_idx[f];
            r += (jf < ie) || (jf == ie && f < e);
        }
        b_idx[r] = ie;
        b_val[r] = a_val[e];
    }
    __syncthreads();

    const int lane = threadIdx.x & 63;
    const int wave = threadIdx.x >> 6;

    // Lane l owns embedding components l and l+64 (K=128).
    float u0 = 0.f, u1 = 0.f;   // u_vec
    float t0 = 0.f, t1 = 0.f;   // t_vec
    float s0 = 0.f, s1 = 0.f;   // s
    float sqp = 0.f;            // partial of sq over owned k
    float bias = 0.f;           // uniform within wave
    for (int e = wave; e < m; e += 4) {
        const int i   = b_idx[e];   // uniform across wave -> no divergence
        const float v = b_val[e];
        bias += v * w_bias[i];
        if (i < NUSR) {
            const float* r = uV + (size_t)i * KDIM;
            u0 += v * r[lane]; u1 += v * r[lane + 64];
        } else if (i < NUSR + NITM) {
            const float* r = bV + (size_t)(i - NUSR) * KDIM;
            t0 += v * r[lane]; t1 += v * r[lane + 64];
        } else {
            const float* r = bV + (size_t)(i - NUSR - NITM) * KDIM;
            const float a = r[lane], b = r[lane + 64];
            s0 += v * a; s1 += v * b;
            sqp += v * (a * a + b * b);
        }
    }
    part[0][wave][lane] = u0;  part[1][wave][lane] = u1;
    part[2][wave][lane] = t0;  part[3][wave][lane] = t1;
    part[4][wave][lane] = s0;  part[5][wave][lane] = s1;
    part[6][wave][lane] = sqp;
    if (lane == 0) bias_part[wave] = bias;
    __syncthreads();
    if (wave != 0) return;

    const float U0 = part[0][0][lane] + part[0][1][lane] + part[0][2][lane] + part[0][3][lane];
    const float U1 = part[1][0][lane] + part[1][1][lane] + part[1][2][lane] + part[1][3][lane];
    const float T0 = part[2][0][lane] + part[2][1][lane] + part[2][2][lane] + part[2][3][lane];
    const float T1 = part[3][0][lane] + part[3][1][lane] + part[3][2][lane] + part[3][3][lane];
    const float S0 = part[4][0][lane] + part[4][1][lane] + part[4][2][lane] + part[4][3][lane];
    const float S1 = part[5][0][lane] + part[5][1][lane] + part[5][2][lane] + part[5][3][lane];
    float sq = part[6][0][lane] + part[6][1][lane] + part[6][2][lane] + part[6][3][lane];
    const float BIAS = bias_part[0] + bias_part[1] + bias_part[2] + bias_part[3];

    float ut = U0 * T0 + U1 * T1;   // dot(u_vec, t_vec)
    float tb = T0 * S0 + T1 * S1;   // dot(t_vec, s)
    float ss = S0 * S0 + S1 * S1;   // dot(s, s)
    float ub = U0 * S0 + U1 * S1;   // dot(u_vec, s)
    #pragma unroll
    for (int off = 32; off > 0; off >>= 1) {
        ut += __shfl_down(ut, off);
        tb += __shfl_down(tb, off);
        ss += __shfl_down(ss, off);
        ub += __shfl_down(ub, off);
        sq += __shfl_down(sq, off);
    }
    if (lane == 0) {
        out[0] = w0[0] + BIAS + ut + tb + 0.5f * (ss - sq) + ub;
    }
}

extern "C" void kernel_launch(void* const* d_in, const int* in_sizes, int n_in,
                              void* d_out, int out_size, void* d_ws, size_t ws_size,
                              hipStream_t stream) {
    // inputs: 0:x 1:delta(unused) 2:pmi(unused) 3:w_0 4:w_bias 5:u_V 6:b_V
    const float* x      = (const float*)d_in[0];
    const float* w0     = (const float*)d_in[3];
    const float* w_bias = (const float*)d_in[4];
    const float* uV     = (const float*)d_in[5];
    const float* bV     = (const float*)d_in[6];
    float* out = (float*)d_out;
    const int p = in_sizes[0];

    char* ws = (char*)d_ws;
    int* cnt  = (int*)(ws + 0);
    int* done = (int*)(ws + 64);
    int cap = MAXNZ;
    const int avail = (int)((ws_size > 128 ? ws_size - 128 : 0) / 8);
    if (avail < cap) cap = avail;
    int*   idxs = (int*)(ws + 128);
    float* vals = (float*)(ws + 128 + (size_t)cap * 4);

    // zero cnt + done each call (ws is poisoned before timing)
    hipMemsetAsync(ws, 0, 128, stream);

    const int n4 = (p + 3) / 4;
    const int blocks = (n4 + 255) / 256;
    k_fused<<<blocks, 256, 0, stream>>>(x, p, cnt, done, idxs, vals, cap,
                                        w0, w_bias, uV, bV, out, blocks);
}

// Round 3
// 19.864 us; speedup vs baseline: 4.4338x; 1.7018x over previous
//
#include <hip/hip_runtime.h>

// Sparse FM scorer: x (p=900000) has exactly ~52 nonzeros (1 user one-hot,
// 1 item one-hot, 50-item basket). All output terms are linear/bilinear in
// the nonzeros.
//
// Kernel A: scan x; each wave compacts its nonzeros deterministically via
//           ballot+popcount into a fixed per-wave slot region. No atomics,
//           no fences, no zero-init needed (counts written unconditionally).
// Kernel B: one block; prefix-scan wave counts, compact pairs to LDS,
//           batched independent row gather (8 float4 loads in flight per
//           thread), 4-wave accumulate, shuffle reduce, write y.

#define NUSR 500000
#define NITM 200000
#define KDIM 128
#define WSLOT 16     // pair slots per wave (wave covers 512 floats; ~0.5 nz expected)
#define MAXNZ 64     // total nonzero capacity (actual: 52)
#define KPT   8      // counts per thread in kernel B (256*8=2048 >= nwaves)

__global__ __launch_bounds__(256) void k_scan(
        const float* __restrict__ x, int p,
        int* __restrict__ counts, int* __restrict__ pidx,
        float* __restrict__ pval) {
    const int tid  = threadIdx.x;
    const int lane = tid & 63;
    const int gw   = blockIdx.x * 4 + (tid >> 6);   // global wave id
    const int nf4  = p >> 2;
    int wcount = 0;
    #pragma unroll
    for (int r = 0; r < 2; r++) {
        const int chunk = blockIdx.x * 512 + r * 256 + tid;  // float4 id
        float v[4] = {0.f, 0.f, 0.f, 0.f};
        if (chunk < nf4) {
            const float4 f = reinterpret_cast<const float4*>(x)[chunk];
            v[0] = f.x; v[1] = f.y; v[2] = f.z; v[3] = f.w;
        } else if (chunk * 4 < p) {            // ragged tail (p % 4 != 0)
            #pragma unroll
            for (int j = 0; j < 4; j++)
                if (chunk * 4 + j < p) v[j] = x[chunk * 4 + j];
        }
        #pragma unroll
        for (int j = 0; j < 4; j++) {
            const bool nz = (v[j] != 0.0f);
            const unsigned long long bm = __ballot(nz);
            if (nz) {
                const int rank = wcount +
                    __popcll(bm & ((1ull << lane) - 1ull));
                if (rank < WSLOT) {
                    pidx[gw * WSLOT + rank] = chunk * 4 + j;
                    pval[gw * WSLOT + rank] = v[j];
                }
            }
            wcount += __popcll(bm);
        }
    }
    if (lane == 0) counts[gw] = wcount;
}

__global__ __launch_bounds__(256) void k_final(
        const int* __restrict__ counts, const int* __restrict__ pidx,
        const float* __restrict__ pval, int nwaves,
        const float* __restrict__ w0, const float* __restrict__ w_bias,
        const float* __restrict__ uV, const float* __restrict__ bV,
        float* __restrict__ out) {
    __shared__ int   c_idx[MAXNZ];
    __shared__ float c_val[MAXNZ];
    __shared__ float wb[MAXNZ];
    __shared__ float rows[MAXNZ][KDIM];   // 32 KB staged embedding rows
    __shared__ int   sscan[256];
    __shared__ int   s_m;
    __shared__ float part[7][4][64];
    const int t = threadIdx.x;

    // ---- 1. load per-wave counts (independent loads, one latency batch) --
    int cl[KPT]; int csum = 0;
    #pragma unroll
    for (int k = 0; k < KPT; k++) {
        const int w = t * KPT + k;
        int c = (w < nwaves) ? counts[w] : 0;
        c = min(max(c, 0), WSLOT);
        cl[k] = c; csum += c;
    }
    sscan[t] = csum;
    __syncthreads();
    // ---- 2. Hillis-Steele inclusive scan over 256 thread sums ----
    for (int d = 1; d < 256; d <<= 1) {
        const int add = (t >= d) ? sscan[t - d] : 0;
        __syncthreads();
        sscan[t] += add;
        __syncthreads();
    }
    const int total = sscan[255];
    int base = sscan[t] - csum;            // exclusive prefix
    if (t == 0) s_m = (total > MAXNZ) ? MAXNZ : total;
    // ---- 3. compact pairs into LDS (deterministic order) ----
    #pragma unroll
    for (int k = 0; k < KPT; k++) {
        const int w = t * KPT + k;
        for (int q = 0; q < cl[k]; q++) {
            if (base < MAXNZ) {
                c_idx[base] = pidx[w * WSLOT + q];
                c_val[base] = pval[w * WSLOT + q];
            }
            base++;
        }
    }
    __syncthreads();
    const int m = s_m;

    if (m > 0) {
        // ---- 4. gather: w_bias (1 per entry) + rows (8 indep f4/thread) --
        if (t < m) wb[t] = w_bias[c_idx[t]];
        const float* srcs[8]; float4 tmp[8]; int dste[8], dstc[8];
        #pragma unroll
        for (int r = 0; r < 8; r++) {
            const int q   = t + r * 256;          // q in [0, m*32)
            const bool act = (q < m * 32);
            const int e = act ? (q >> 5) : 0;
            const int c = act ? (q & 31) : 0;
            const int i = c_idx[e];
            const float* rp;
            if (i < NUSR)             rp = uV + (size_t)i * KDIM;
            else if (i < NUSR + NITM) rp = bV + (size_t)(i - NUSR) * KDIM;
            else                      rp = bV + (size_t)(i - NUSR - NITM) * KDIM;
            srcs[r] = act ? (rp + c * 4) : uV;    // dummy-safe when inactive
            dste[r] = act ? e : -1; dstc[r] = c;
        }
        #pragma unroll
        for (int r = 0; r < 8; r++)               // all 8 loads in flight
            tmp[r] = *reinterpret_cast<const float4*>(srcs[r]);
        #pragma unroll
        for (int r = 0; r < 8; r++)
            if (dste[r] >= 0)
                *reinterpret_cast<float4*>(&rows[dste[r]][dstc[r] * 4]) = tmp[r];
    }
    __syncthreads();

    // ---- 5. 4-wave accumulate from LDS (lane l owns components l, l+64) --
    const int lane = t & 63, wave = t >> 6;
    float u0 = 0.f, u1 = 0.f, t0 = 0.f, t1 = 0.f, s0 = 0.f, s1 = 0.f, sqp = 0.f;
    for (int e = wave; e < m; e += 4) {
        const int i   = c_idx[e];                 // uniform across wave
        const float v = c_val[e];
        const float a = rows[e][lane], b = rows[e][lane + 64];
        if (i < NUSR)             { u0 += v * a; u1 += v * b; }
        else if (i < NUSR + NITM) { t0 += v * a; t1 += v * b; }
        else { s0 += v * a; s1 += v * b; sqp += v * (a * a + b * b); }
    }
    part[0][wave][lane] = u0; part[1][wave][lane] = u1;
    part[2][wave][lane] = t0; part[3][wave][lane] = t1;
    part[4][wave][lane] = s0; part[5][wave][lane] = s1;
    part[6][wave][lane] = sqp;
    __syncthreads();
    if (wave != 0) return;

    const float U0 = part[0][0][lane] + part[0][1][lane] + part[0][2][lane] + part[0][3][lane];
    const float U1 = part[1][0][lane] + part[1][1][lane] + part[1][2][lane] + part[1][3][lane];
    const float T0 = part[2][0][lane] + part[2][1][lane] + part[2][2][lane] + part[2][3][lane];
    const float T1 = part[3][0][lane] + part[3][1][lane] + part[3][2][lane] + part[3][3][lane];
    const float S0 = part[4][0][lane] + part[4][1][lane] + part[4][2][lane] + part[4][3][lane];
    const float S1 = part[5][0][lane] + part[5][1][lane] + part[5][2][lane] + part[5][3][lane];
    float sq = part[6][0][lane] + part[6][1][lane] + part[6][2][lane] + part[6][3][lane];

    float ut = U0 * T0 + U1 * T1;   // dot(u_vec, t_vec)
    float tb = T0 * S0 + T1 * S1;   // dot(t_vec, s)
    float ss = S0 * S0 + S1 * S1;   // dot(s, s)
    float ub = U0 * S0 + U1 * S1;   // dot(u_vec, s)
    float bp = (lane < m) ? wb[lane] * c_val[lane] : 0.f;  // bias partials
    #pragma unroll
    for (int off = 32; off > 0; off >>= 1) {
        ut += __shfl_down(ut, off);
        tb += __shfl_down(tb, off);
        ss += __shfl_down(ss, off);
        ub += __shfl_down(ub, off);
        sq += __shfl_down(sq, off);
        bp += __shfl_down(bp, off);
    }
    if (lane == 0)
        out[0] = w0[0] + bp + ut + tb + 0.5f * (ss - sq) + ub;
}

extern "C" void kernel_launch(void* const* d_in, const int* in_sizes, int n_in,
                              void* d_out, int out_size, void* d_ws, size_t ws_size,
                              hipStream_t stream) {
    // inputs: 0:x 1:delta(unused) 2:pmi(unused) 3:w_0 4:w_bias 5:u_V 6:b_V
    const float* x      = (const float*)d_in[0];
    const float* w0     = (const float*)d_in[3];
    const float* w_bias = (const float*)d_in[4];
    const float* uV     = (const float*)d_in[5];
    const float* bV     = (const float*)d_in[6];
    float* out = (float*)d_out;
    const int p = in_sizes[0];

    const int blocks = (p + 2047) / 2048;   // 2048 floats per 256-thr block
    const int nwaves = blocks * 4;

    // ws layout (no initialization required by design):
    //   counts: [0, 64K)   pidx: [64K, 512K)   pval: [512K, 1M)
    char* ws = (char*)d_ws;
    int*   counts = (int*)  (ws);
    int*   pidx   = (int*)  (ws + (64u  << 10));
    float* pval   = (float*)(ws + (512u << 10));

    k_scan<<<blocks, 256, 0, stream>>>(x, p, counts, pidx, pval);
    k_final<<<1, 256, 0, stream>>>(counts, pidx, pval, nwaves,
                                   w0, w_bias, uV, bV, out);
}